// Round 3
// baseline (655.097 us; speedup 1.0000x reference)
//
#include <hip/hip_runtime.h>
#include <math.h>

// B=8, O=8, S=32, C=64, H=32, W=32, HID=C
#define Bc 8
#define Oc 8
#define Sc 32
#define Cc 64
#define HWc 1024
#define NBLK (Bc*Oc*Sc)     // 2048 blocks, one (b,o,s) sample each

typedef float f4 __attribute__((ext_vector_type(4)));

static __device__ __forceinline__ float hsum(f4 a) { return (a.x + a.y) + (a.z + a.w); }
static __device__ __forceinline__ float hmax(f4 a) { return fmaxf(fmaxf(a.x, a.y), fmaxf(a.z, a.w)); }
static __device__ __forceinline__ f4 vmax4(f4 a, f4 b) {
    f4 r; r.x = fmaxf(a.x, b.x); r.y = fmaxf(a.y, b.y);
    r.z = fmaxf(a.z, b.z); r.w = fmaxf(a.w, b.w); return r;
}

// Phase 1: 4 waves x 16 channels, 8 groups of 2 channels. Explicit 2-deep
//          software pipeline: group g+1's 8 nt-loads issue BEFORE group g's
//          butterfly reduce, keeping ~8 KB/wave in flight through the
//          reduce stretch (the round-2 version had zero loads outstanding
//          during each ~250-cycle reduce).
// Phase 2: wave0 = mean path, wave1 = max path, combined at the end.
__global__ __launch_bounds__(256, 4) void ca_fused(const float* __restrict__ x,
                                                   const float* __restrict__ w1,
                                                   const float* __restrict__ w2,
                                                   float* __restrict__ out) {
    __shared__ float s_mean[Cc];
    __shared__ float s_max[Cc];
    __shared__ float s_hm[Cc];
    __shared__ float s_hx[Cc];
    __shared__ float s_ax[Cc];

    const int blk  = blockIdx.x;            // (b*O + o)*S + s
    const int o    = (blk / Sc) % Oc;       // group index
    const int tid  = threadIdx.x;
    const int wave = tid >> 6;
    const int lane = tid & 63;

    const f4* xb = (const f4*)(x + (size_t)blk * (Cc * HWc)) + lane;

    // ---- Phase 1: pooling with software pipeline ----
    f4 cur[8];
    {
        const f4* p0 = xb + (size_t)(wave * 16) * 256;   // 256 f4 per channel
        #pragma unroll
        for (int j = 0; j < 4; ++j) {
            cur[j]     = __builtin_nontemporal_load(p0 + j * 64);
            cur[4 + j] = __builtin_nontemporal_load(p0 + 256 + j * 64);
        }
    }

    #pragma unroll
    for (int g = 0; g < 8; ++g) {
        f4 nxt[8];
        if (g < 7) {
            const f4* p0 = xb + (size_t)(wave * 16 + (g + 1) * 2) * 256;
            #pragma unroll
            for (int j = 0; j < 4; ++j) {
                nxt[j]     = __builtin_nontemporal_load(p0 + j * 64);
                nxt[4 + j] = __builtin_nontemporal_load(p0 + 256 + j * 64);
            }
        }

        // reduce current group (channels c0, c0+1)
        const int c0 = wave * 16 + g * 2;
        f4 sa = (cur[0] + cur[1]) + (cur[2] + cur[3]);
        f4 ma = vmax4(vmax4(cur[0], cur[1]), vmax4(cur[2], cur[3]));
        f4 sb = (cur[4] + cur[5]) + (cur[6] + cur[7]);
        f4 mb = vmax4(vmax4(cur[4], cur[5]), vmax4(cur[6], cur[7]));

        float s0 = hsum(sa), m0 = hmax(ma);
        float s1 = hsum(sb), m1 = hmax(mb);

        #pragma unroll
        for (int m = 32; m >= 1; m >>= 1) {
            s0 += __shfl_xor(s0, m, 64);
            s1 += __shfl_xor(s1, m, 64);
            m0 = fmaxf(m0, __shfl_xor(m0, m, 64));
            m1 = fmaxf(m1, __shfl_xor(m1, m, 64));
        }
        if (lane == 0) {
            s_mean[c0]     = s0 * (1.0f / 1024.0f);
            s_mean[c0 + 1] = s1 * (1.0f / 1024.0f);
            s_max[c0]      = m0;
            s_max[c0 + 1]  = m1;
        }

        #pragma unroll
        for (int j = 0; j < 8; ++j) cur[j] = nxt[j];
    }
    __syncthreads();

    // ---- Phase 2: grouped 64->64->64 MLP; wave0=mean path, wave1=max path ----
    float acc2 = 0.f;
    if (wave < 2) {
        const float* src = wave ? s_max : s_mean;
        const float* w1o = w1 + ((size_t)o * Cc + lane) * Cc;
        float a = 0.f;
        #pragma unroll
        for (int c2 = 0; c2 < Cc; ++c2) a = fmaf(src[c2], w1o[c2], a);
        (wave ? s_hx : s_hm)[lane] = fmaxf(a, 0.f);
    }
    __syncthreads();

    if (wave < 2) {
        const float* src = wave ? s_hx : s_hm;
        const float* w2o = w2 + ((size_t)o * Cc + lane) * Cc;
        #pragma unroll
        for (int h = 0; h < Cc; ++h) acc2 = fmaf(src[h], w2o[h], acc2);
        if (wave == 1) s_ax[lane] = acc2;
    }
    __syncthreads();

    if (wave == 0) {
        const float z = acc2 + s_ax[lane];
        out[(size_t)blk * Cc + lane] = 1.0f / (1.0f + __expf(-z));
    }
}

extern "C" void kernel_launch(void* const* d_in, const int* in_sizes, int n_in,
                              void* d_out, int out_size, void* d_ws, size_t ws_size,
                              hipStream_t stream) {
    const float* x  = (const float*)d_in[0];
    const float* w1 = (const float*)d_in[1];
    const float* w2 = (const float*)d_in[2];
    float* out = (float*)d_out;

    ca_fused<<<NBLK, 256, 0, stream>>>(x, w1, w2, out);
}

// Round 4
// 654.795 us; speedup vs baseline: 1.0005x; 1.0005x over previous
//
#include <hip/hip_runtime.h>
#include <math.h>

// B=8, O=8, S=32, C=64, H=32, W=32, HID=C
#define Bc 8
#define Oc 8
#define Sc 32
#define Cc 64
#define HWc 1024
#define NBLK (Bc*Oc*Sc)     // 2048 blocks, one (b,o,s) sample each

typedef float f4 __attribute__((ext_vector_type(4)));

static __device__ __forceinline__ float hsum(f4 a) { return (a.x + a.y) + (a.z + a.w); }
static __device__ __forceinline__ float hmax(f4 a) { return fmaxf(fmaxf(a.x, a.y), fmaxf(a.z, a.w)); }
static __device__ __forceinline__ f4 vmax4(f4 a, f4 b) {
    f4 r; r.x = fmaxf(a.x, b.x); r.y = fmaxf(a.y, b.y);
    r.z = fmaxf(a.z, b.z); r.w = fmaxf(a.w, b.w); return r;
}

// Phase 1: each wave owns 16 channels, processed 4 at a time. The wave is
//          split into four 16-lane groups, one channel per group: lane
//          l = 16*csub + t reads f4[t + 16k], k=0..15 (256 B contiguous per
//          group per instruction), accumulates sum/max in registers (2 VALU
//          per load), then a 4-step butterfly (masks 8,4,2,1) inside the
//          16-lane group. 6x fewer ds-shuffles and ~half the live VGPRs of
//          the round-3 version -> higher occupancy, more lines in flight.
// Phase 2: wave0 = mean path, wave1 = max path, combined at the end.
__global__ __launch_bounds__(256) void ca_fused(const float* __restrict__ x,
                                                const float* __restrict__ w1,
                                                const float* __restrict__ w2,
                                                float* __restrict__ out) {
    __shared__ float s_mean[Cc];
    __shared__ float s_max[Cc];
    __shared__ float s_hm[Cc];
    __shared__ float s_hx[Cc];
    __shared__ float s_ax[Cc];

    const int blk  = blockIdx.x;            // (b*O + o)*S + s
    const int o    = (blk / Sc) % Oc;       // group index
    const int tid  = threadIdx.x;
    const int wave = tid >> 6;
    const int lane = tid & 63;
    const int csub = lane >> 4;             // which of 4 channels in the group
    const int t    = lane & 15;             // position within 16-lane group

    const f4* xb = (const f4*)(x + (size_t)blk * (Cc * HWc));

    // ---- Phase 1: pooling ----
    #pragma unroll
    for (int g = 0; g < 4; ++g) {
        const int c = wave * 16 + g * 4 + csub;
        const f4* p = xb + (size_t)c * 256 + t;   // 256 f4 per channel

        // 16 f4 per lane, 4 independent accumulator streams for ILP
        f4 v0 = __builtin_nontemporal_load(p);
        f4 v1 = __builtin_nontemporal_load(p + 16);
        f4 v2 = __builtin_nontemporal_load(p + 32);
        f4 v3 = __builtin_nontemporal_load(p + 48);
        f4 s0 = v0, m0 = v0;
        f4 s1 = v1, m1 = v1;
        f4 s2 = v2, m2 = v2;
        f4 s3 = v3, m3 = v3;
        #pragma unroll
        for (int k = 4; k < 16; k += 4) {
            f4 a = __builtin_nontemporal_load(p + (k + 0) * 16);
            f4 b = __builtin_nontemporal_load(p + (k + 1) * 16);
            f4 cc = __builtin_nontemporal_load(p + (k + 2) * 16);
            f4 d = __builtin_nontemporal_load(p + (k + 3) * 16);
            s0 += a;  m0 = vmax4(m0, a);
            s1 += b;  m1 = vmax4(m1, b);
            s2 += cc; m2 = vmax4(m2, cc);
            s3 += d;  m3 = vmax4(m3, d);
        }
        f4 sv = (s0 + s1) + (s2 + s3);
        f4 mv = vmax4(vmax4(m0, m1), vmax4(m2, m3));
        float sum = hsum(sv);
        float mx  = hmax(mv);

        // 4-step butterfly within the 16-lane group
        #pragma unroll
        for (int m = 8; m >= 1; m >>= 1) {
            sum += __shfl_xor(sum, m, 64);
            mx   = fmaxf(mx, __shfl_xor(mx, m, 64));
        }
        if (t == 0) {
            s_mean[c] = sum * (1.0f / 1024.0f);
            s_max[c]  = mx;
        }
    }
    __syncthreads();

    // ---- Phase 2: grouped 64->64->64 MLP; wave0=mean path, wave1=max path ----
    float acc2 = 0.f;
    if (wave < 2) {
        const float* src = wave ? s_max : s_mean;
        const float* w1o = w1 + ((size_t)o * Cc + lane) * Cc;
        float a = 0.f;
        #pragma unroll
        for (int c2 = 0; c2 < Cc; ++c2) a = fmaf(src[c2], w1o[c2], a);
        (wave ? s_hx : s_hm)[lane] = fmaxf(a, 0.f);
    }
    __syncthreads();

    if (wave < 2) {
        const float* src = wave ? s_hx : s_hm;
        const float* w2o = w2 + ((size_t)o * Cc + lane) * Cc;
        #pragma unroll
        for (int h = 0; h < Cc; ++h) acc2 = fmaf(src[h], w2o[h], acc2);
        if (wave == 1) s_ax[lane] = acc2;
    }
    __syncthreads();

    if (wave == 0) {
        const float z = acc2 + s_ax[lane];
        out[(size_t)blk * Cc + lane] = 1.0f / (1.0f + __expf(-z));
    }
}

extern "C" void kernel_launch(void* const* d_in, const int* in_sizes, int n_in,
                              void* d_out, int out_size, void* d_ws, size_t ws_size,
                              hipStream_t stream) {
    const float* x  = (const float*)d_in[0];
    const float* w1 = (const float*)d_in[1];
    const float* w2 = (const float*)d_in[2];
    float* out = (float*)d_out;

    ca_fused<<<NBLK, 256, 0, stream>>>(x, w1, w2, out);
}